// Round 1
// baseline (116.065 us; speedup 1.0000x reference)
//
#include <hip/hip_runtime.h>
#include <math.h>

#define NB 16
#define NA 3
#define NC 80
#define GS 4096                 // 64*64 spatial
#define NPOS (NB * NA * GS)     // 196608
// LDS row stride in floats: 84*4=336 B -> 16B-aligned rows (ds_read_b128 ok),
// and 4*84 % 32 = 16 -> transposed b32 writes are at worst 2-way (free).
#define STR 84

__device__ __forceinline__ float sigmoidf_(float v) {
    return 1.0f / (1.0f + __expf(-v));
}

// Barrier-free per-wave streaming:
//   each wave owns 16 consecutive spatial positions of one (b,a) pair.
//   Reads:  5x global_load_dwordx4 per lane  (lane = 16 channels x 4 float4 slots)
//   LDS:    transposed wave-private tile [pos][ch] (no __syncthreads needed)
//   Writes: 5x dwordx4 per lane, contiguous 16x80 cls tile; lanes 0..15 do box+conf.
__global__ __launch_bounds__(256, 7) void yolo_kernel(const float* __restrict__ x,
                                                      const float* __restrict__ anchors,
                                                      float* __restrict__ out) {
    __shared__ float lds[4][16 * STR];      // 21504 B -> 7 blocks/CU (same as before)
    const int tid = threadIdx.x;
    const int w   = tid >> 6;               // wave id 0..3
    const int l   = tid & 63;               // lane
    const int ba  = blockIdx.x >> 6;        // (b,a) pair 0..47
    const int row = blockIdx.x & 63;        // grid row i
    const int s0  = (row << 6) + (w << 4);  // this wave's 16-position chunk
    const float* __restrict__ xb = x + (size_t)ba * 85 * GS + s0;
    float* const ldsw = lds[w];

    const int chl = l >> 2;                 // channel within 16-group
    const int p4  = l & 3;                  // which float4 (positions p4*4..p4*4+3)
    const float* __restrict__ xc = xb + (size_t)(5 + chl) * GS + p4 * 4;

    // ---- issue all cls loads up front: 5 x dwordx4, 1 KB per wave-instr ----
    float4 v[5];
    #pragma unroll
    for (int k = 0; k < 5; ++k)
        v[k] = *reinterpret_cast<const float4*>(xc + (size_t)k * 16 * GS);

    // ---- box/conf loads: lanes 0..15, one 64B line per channel row ----
    float tx = 0.f, ty = 0.f, tw = 0.f, th = 0.f, tc = 0.f;
    const bool box_lane = (l < 16);
    if (box_lane) {
        tx = xb[0 * GS + l];
        ty = xb[1 * GS + l];
        tw = xb[2 * GS + l];
        th = xb[3 * GS + l];
        tc = xb[4 * GS + l];
    }

    // ---- sigmoid + transposed LDS writes: lds[pos_local][ch] ----
    #pragma unroll
    for (int k = 0; k < 5; ++k) {
        #pragma unroll
        for (int j = 0; j < 4; ++j) {
            const float sv = sigmoidf_((&v[k].x)[j]);
            ldsw[(p4 * 4 + j) * STR + k * 16 + chl] = sv;
        }
    }

    // ---- box + conf output (lanes 0..15), coalesced 256B / 64B ----
    if (box_lane) {
        const int p = s0 + l;               // spatial index within (b,a)
        const int t = ba * GS + p;          // global position index
        const int a = ba % NA;
        float4 box;
        box.x = (sigmoidf_(tx) + (float)(p >> 6)) * (1.0f / 64.0f);  // grid_x = row
        box.y = (sigmoidf_(ty) + (float)(p & 63)) * (1.0f / 64.0f);  // grid_y = col
        box.z = __expf(tw) * anchors[a * 2 + 0];
        box.w = __expf(th) * anchors[a * 2 + 1];
        reinterpret_cast<float4*>(out)[t] = box;
        out[(size_t)NPOS * 4 + t] = sigmoidf_(tc);
    }

    // ---- cls writes: wave-private LDS, no barrier; 5 x (b128 read + dwordx4 store)
    // 16x80 floats = 320 float4, contiguous region per wave.
    float4* __restrict__ out4 =
        reinterpret_cast<float4*>(out + (size_t)NPOS * 5) + (size_t)(ba * GS + s0) * 20;
    #pragma unroll
    for (int k = 0; k < 5; ++k) {
        const int o4 = (k << 6) + l;        // 0..319
        const int o  = o4 << 2;
        const int p  = o / 80;              // local position 0..15 (magic-mul)
        const int ch = o - p * 80;          // channel, multiple of 4
        out4[o4] = *reinterpret_cast<const float4*>(&ldsw[p * STR + ch]);
    }
}

extern "C" void kernel_launch(void* const* d_in, const int* in_sizes, int n_in,
                              void* d_out, int out_size, void* d_ws, size_t ws_size,
                              hipStream_t stream) {
    const float* x       = (const float*)d_in[0];
    const float* anchors = (const float*)d_in[1];
    float* out           = (float*)d_out;
    const int blocks = NB * NA * 64;        // 3072 blocks, one (b,a,row); 4 wave-chunks each
    yolo_kernel<<<blocks, 256, 0, stream>>>(x, anchors, out);
}

// Round 2
// 112.117 us; speedup vs baseline: 1.0352x; 1.0352x over previous
//
#include <hip/hip_runtime.h>
#include <math.h>

#define NB 16
#define NA 3
#define NC 80
#define GS 4096                 // 64*64 spatial
#define NPOS (NB * NA * GS)     // 196608
#define POSB 128                // positions per block (2 grid rows) -> 512B read segments
#define LSTR 133                // LDS row stride (odd): write-phase gather ~2.5-way, write side 4-way

__device__ __forceinline__ float sigmoidf_(float v) {
    return 1.0f / (1.0f + __expf(-v));
}

// Block = one (b,a) pair x 128 consecutive spatial positions (two grid rows).
// Read:  80 cls planes as 512-B segments, dwordx4 (10 loads/thread), sigmoid -> LDS [ch][pos].
// Box:   waves 0-1 (tid<128) load ch0..4 directly, compute, store pre-barrier.
// Write: 128x80 cls tile = contiguous 40KB region, dwordx4 stores.
__global__ __launch_bounds__(256) void yolo_kernel(const float* __restrict__ x,
                                                   const float* __restrict__ anchors,
                                                   float* __restrict__ out) {
    __shared__ float lds[NC * LSTR];        // 42560 B -> 3 blocks/CU
    const int tid   = threadIdx.x;
    const int ba    = blockIdx.x >> 5;      // (b,a) pair 0..47
    const int chunk = blockIdx.x & 31;      // which 128-pos chunk 0..31
    const int s0    = chunk << 7;
    const float* __restrict__ xb = x + (size_t)ba * 85 * GS + s0;

    // ---- box loads first (oldest in vmcnt queue, retire early) ----
    float tx = 0.f, ty = 0.f, tw = 0.f, th = 0.f, tc = 0.f;
    const bool box_lane = (tid < POSB);
    if (box_lane) {
        tx = xb[0 * GS + tid];
        ty = xb[1 * GS + tid];
        tw = xb[2 * GS + tid];
        th = xb[3 * GS + tid];
        tc = xb[4 * GS + tid];
    }

    // ---- cls loads: lane = (chq = tid>>5, p4 = tid&31); channel = chq + 8k ----
    // per wave-instr: 2 channels x 512 B contiguous, 16KB-strided planes
    const int p4  = tid & 31;
    const int chq = tid >> 5;
    const float* __restrict__ xc = xb + (size_t)(5 + chq) * GS + p4 * 4;
    float4 v[10];
    #pragma unroll
    for (int k = 0; k < 10; ++k)
        v[k] = *reinterpret_cast<const float4*>(xc + (size_t)(8 * k) * GS);

    // ---- box compute + store (independent of LDS, pre-barrier) ----
    if (box_lane) {
        const int p = s0 + tid;             // spatial index within (b,a)
        const int t = ba * GS + p;          // global position index
        const int a = ba % NA;
        float4 box;
        box.x = (sigmoidf_(tx) + (float)(p >> 6)) * (1.0f / 64.0f);  // grid_x = row
        box.y = (sigmoidf_(ty) + (float)(p & 63)) * (1.0f / 64.0f);  // grid_y = col
        box.z = __expf(tw) * anchors[a * 2 + 0];
        box.w = __expf(th) * anchors[a * 2 + 1];
        reinterpret_cast<float4*>(out)[t] = box;
        out[(size_t)NPOS * 4 + t] = sigmoidf_(tc);
    }

    // ---- sigmoid + LDS transpose store: lds[ch][pos] ----
    #pragma unroll
    for (int k = 0; k < 10; ++k) {
        const int ch = chq + 8 * k;
        float* lr = &lds[ch * LSTR + p4 * 4];
        lr[0] = sigmoidf_(v[k].x);
        lr[1] = sigmoidf_(v[k].y);
        lr[2] = sigmoidf_(v[k].z);
        lr[3] = sigmoidf_(v[k].w);
    }

    __syncthreads();

    // ---- cls writes: contiguous 40KB tile, 10 x dwordx4 per thread ----
    float4* __restrict__ out4 =
        reinterpret_cast<float4*>(out + (size_t)NPOS * 5) + (size_t)(ba * GS + s0) * 20;
    #pragma unroll
    for (int k = 0; k < 10; ++k) {
        const int o4 = tid + (k << 8);      // 0..2559
        const int p  = o4 / 20;             // local position 0..127 (magic-mul)
        const int c4 = o4 - p * 20;         // channel quad 0..19
        float4 w4;
        w4.x = lds[(c4 * 4 + 0) * LSTR + p];
        w4.y = lds[(c4 * 4 + 1) * LSTR + p];
        w4.z = lds[(c4 * 4 + 2) * LSTR + p];
        w4.w = lds[(c4 * 4 + 3) * LSTR + p];
        out4[o4] = w4;
    }
}

extern "C" void kernel_launch(void* const* d_in, const int* in_sizes, int n_in,
                              void* d_out, int out_size, void* d_ws, size_t ws_size,
                              hipStream_t stream) {
    const float* x       = (const float*)d_in[0];
    const float* anchors = (const float*)d_in[1];
    float* out           = (float*)d_out;
    const int blocks = NB * NA * 32;        // 1536 blocks: one per (b,a, 128-pos chunk)
    yolo_kernel<<<blocks, 256, 0, stream>>>(x, anchors, out);
}